// Round 2
// baseline (712.957 us; speedup 1.0000x reference)
//
#include <hip/hip_runtime.h>
#include <hip/hip_bf16.h>
#include <stdint.h>

// LightningIndexer: importance[b,q,k] = sum_h w[b,q,h] * relu( q_h[b,q,:] . kv[b,k,:] )
// B=2, T=4096, C=2048, H=16, D=32.
// Identity used: w*relu(s) = (w/2)*s + (w/2)*|s|  ->  linear part folded into ONE extra
// MFMA with Qt = sum_h (w_h/2) q_h ; abs part is a single fma-with-abs-modifier per reg.
// Pipeline: pack -> proj GEMM -> combine(Qt) -> fused scores.

typedef __attribute__((ext_vector_type(8))) short bf16x8;
typedef __attribute__((ext_vector_type(4))) float f32x4;

#define NPAD 576   // 512 q | 32 k | 16 w | 16 zero pad  (9 tiles of 64)
#define KCOL 512
#define WCOL 544

__device__ __forceinline__ unsigned short f2bf(float f) {
  union { float f; unsigned u; } c; c.f = f;
  unsigned u = c.u;
  u += 0x7FFFu + ((u >> 16) & 1u);
  return (unsigned short)(u >> 16);
}
__device__ __forceinline__ float bf2f(unsigned short u) {
  union { unsigned u; float f; } c; c.u = ((unsigned)u) << 16;
  return c.f;
}
__device__ __forceinline__ void async_copy16(void* lds, const void* g) {
  __builtin_amdgcn_global_load_lds(
      (const __attribute__((address_space(1))) unsigned*)g,
      (__attribute__((address_space(3))) unsigned*)lds, 16, 0, 0);
}

// ---------------- kernel 1: cast x to bf16, pack Wq/Wk/Ww (+zero pad) ----------------
__global__ __launch_bounds__(256) void pack_kernel(
    const float* __restrict__ x, const float* __restrict__ Wq,
    const float* __restrict__ Wk, const float* __restrict__ Ww,
    unsigned short* __restrict__ xb, unsigned short* __restrict__ Wp) {
  const int64_t NX4 = 16777216 / 4;
  int64_t i = (int64_t)blockIdx.x * 256 + threadIdx.x;
  if (i < NX4) {
    float4 v = ((const float4*)x)[i];
    ushort4 o;
    o.x = f2bf(v.x); o.y = f2bf(v.y); o.z = f2bf(v.z); o.w = f2bf(v.w);
    ((ushort4*)xb)[i] = o;
  } else {
    int p = (int)(i - NX4);                  // 0 .. 576*512-1
    int row = p >> 9;
    int col = (p & 511) << 2;
    float4 v = make_float4(0.f, 0.f, 0.f, 0.f);
    if (row < 512)      v = *(const float4*)(Wq + (int64_t)row * 2048 + col);
    else if (row < 544) v = *(const float4*)(Wk + (int64_t)(row - 512) * 2048 + col);
    else if (row < 560) v = *(const float4*)(Ww + (int64_t)(row - 544) * 2048 + col);
    ushort4 o;
    o.x = f2bf(v.x); o.y = f2bf(v.y); o.z = f2bf(v.z); o.w = f2bf(v.w);
    ((ushort4*)Wp)[p] = o;
  }
}

// ---------------- kernel 2: qkw = x @ Wp^T  (8192 x 576 x 2048, bf16 MFMA) ----------------
// tile 128m x 64n, BK=64 (two k-half LDS tiles to keep the m97 ds_read pattern).
__global__ __launch_bounds__(256) void gemm_proj(
    const unsigned short* __restrict__ xb, const unsigned short* __restrict__ Wp,
    unsigned short* __restrict__ qkwb, float* __restrict__ wf) {
  __shared__ short lA[2 * 128 * 32];   // 16 KB, [kh][row][32]
  __shared__ short lB[2 * 64 * 32];    //  8 KB
  const int tid = threadIdx.x;
  const int lane = tid & 63;
  const int l15 = lane & 15, quad = lane >> 4;
  const int wm = tid >> 6;             // wave id = m-strip (4 x 32 rows)
  const int n0 = blockIdx.x * 64, m0 = blockIdx.y * 128;

  // staging map: A chunks c in [0,1024): kh=c>>9, row=(c>>2)&127, cc=c&3
  //              B chunks c in [0,512):  kh=c>>8, row=(c>>2)&63,  cc=c&3
  const unsigned short* gA[4];
  const unsigned short* gB[2];
  int cA[4], cB[2];
#pragma unroll
  for (int u = 0; u < 4; ++u) {
    int c = tid + u * 256;
    cA[u] = c;
    int kh = c >> 9, row = (c >> 2) & 127, cc = c & 3;
    gA[u] = xb + (int64_t)(m0 + row) * 2048 + kh * 32 + cc * 8;
  }
#pragma unroll
  for (int u = 0; u < 2; ++u) {
    int c = tid + u * 256;
    cB[u] = c;
    int kh = c >> 8, row = (c >> 2) & 63, cc = c & 3;
    gB[u] = Wp + (int64_t)(n0 + row) * 2048 + kh * 32 + cc * 8;
  }

  f32x4 acc[2][4] = {};   // wave tile 32m x 64n

  for (int kt = 0; kt < 32; ++kt) {
    const int ko = kt * 64;
#pragma unroll
    for (int u = 0; u < 4; ++u) async_copy16(&lA[cA[u] * 8], gA[u] + ko);
#pragma unroll
    for (int u = 0; u < 2; ++u) async_copy16(&lB[cB[u] * 8], gB[u] + ko);
    __syncthreads();
#pragma unroll
    for (int ks = 0; ks < 2; ++ks) {
      bf16x8 af[2], bfr[4];
#pragma unroll
      for (int i = 0; i < 2; ++i)
        af[i] = *(const bf16x8*)&lA[(ks * 128 + wm * 32 + i * 16 + l15) * 32 + quad * 8];
#pragma unroll
      for (int j = 0; j < 4; ++j)
        bfr[j] = *(const bf16x8*)&lB[(ks * 64 + j * 16 + l15) * 32 + quad * 8];
#pragma unroll
      for (int i = 0; i < 2; ++i)
#pragma unroll
        for (int j = 0; j < 4; ++j)
          acc[i][j] = __builtin_amdgcn_mfma_f32_16x16x32_bf16(af[i], bfr[j], acc[i][j], 0, 0, 0);
    }
    __syncthreads();
  }

#pragma unroll
  for (int i = 0; i < 2; ++i)
#pragma unroll
    for (int j = 0; j < 4; ++j)
#pragma unroll
      for (int r = 0; r < 4; ++r) {
        int m = m0 + wm * 32 + i * 16 + quad * 4 + r;
        int n = n0 + j * 16 + l15;
        float v = acc[i][j][r];
        qkwb[(int64_t)m * NPAD + n] = f2bf(v);
        if (n >= WCOL && n < WCOL + 16) wf[m * 16 + (n - WCOL)] = 0.5f * v;  // w/2, fp32
      }
}

// ---------------- kernel 3: Qt[m,:] = sum_h (w_h/2) * q_h[m,:]  (8192 x 32 bf16) --------
__global__ __launch_bounds__(256) void combine_kernel(
    const unsigned short* __restrict__ qkwb, const float* __restrict__ wf,
    unsigned short* __restrict__ qt) {
  int gid = blockIdx.x * 256 + threadIdx.x;   // 65536 threads
  int m = gid >> 3, dq = (gid & 7) * 4;
  const unsigned short* qrow = qkwb + (int64_t)m * NPAD + dq;
  float s0 = 0, s1 = 0, s2 = 0, s3 = 0;
#pragma unroll
  for (int h = 0; h < 16; ++h) {
    ushort4 qv = *(const ushort4*)(qrow + h * 32);
    float u = wf[m * 16 + h];
    s0 += u * bf2f(qv.x); s1 += u * bf2f(qv.y);
    s2 += u * bf2f(qv.z); s3 += u * bf2f(qv.w);
  }
  ushort4 o; o.x = f2bf(s0); o.y = f2bf(s1); o.z = f2bf(s2); o.w = f2bf(s3);
  *(ushort4*)(qt + (int64_t)m * 32 + dq) = o;
}

// ---------------- kernel 4: fused scores ----------------
// out[q,k] = Qt[q,:].k[k,:]  (one MFMA)  +  sum_h wv[q,h]*|q_h[q,:].k[k,:]|
__global__ __launch_bounds__(256) void scores_kernel(
    const unsigned short* __restrict__ qkwb, const float* __restrict__ wf,
    const unsigned short* __restrict__ qt, float* __restrict__ out) {
  const int kt = blockIdx.x, qtile = blockIdx.y, b = blockIdx.z;
  const int tid = threadIdx.x;
  const int lane = tid & 63;
  const int l15 = lane & 15, quad = lane >> 4;
  const int wave = tid >> 6;
  const int wk = wave & 1, wq = wave >> 1;

  __shared__ float w_lds[16][132];           // [h][q_local], wv = w/2

  const int qrow0 = b * 4096 + qtile * 128;
  const int krow0 = b * 4096 + kt * 128;

  {  // stage wv tile transposed: 128 q x 16 h fp32
    const float4* ws = (const float4*)(wf + (int64_t)qrow0 * 16);
#pragma unroll
    for (int r = 0; r < 2; ++r) {
      int f = tid * 2 + r;
      float4 v = ws[f];
      int row = f >> 2, hb = (f & 3) * 4;
      w_lds[hb + 0][row] = v.x; w_lds[hb + 1][row] = v.y;
      w_lds[hb + 2][row] = v.z; w_lds[hb + 3][row] = v.w;
    }
  }

  // K fragments (shared across heads + linear term), register-resident
  bf16x8 ka[4];
#pragma unroll
  for (int i = 0; i < 4; ++i) {
    int kk = krow0 + wk * 64 + i * 16 + l15;
    ka[i] = *(const bf16x8*)&qkwb[(int64_t)kk * NPAD + KCOL + quad * 8];
  }

  const f32x4 z0 = {0.f, 0.f, 0.f, 0.f};

  // init acc with the linear term: acc = Qt . k
  f32x4 acc[4][4];
  {
#pragma unroll
    for (int j = 0; j < 4; ++j) {
      bf16x8 qtf = *(const bf16x8*)&qt[(int64_t)(qrow0 + wq * 64 + j * 16 + l15) * 32 + quad * 8];
#pragma unroll
      for (int i = 0; i < 4; ++i)
        acc[i][j] = __builtin_amdgcn_mfma_f32_16x16x32_bf16(ka[i], qtf, z0, 0, 0, 0);
    }
  }

  const unsigned short* qbase =
      qkwb + (int64_t)(qrow0 + wq * 64 + l15) * NPAD + quad * 8;

  bf16x8 qa[4], qb[4];
#pragma unroll
  for (int j = 0; j < 4; ++j) qa[j] = *(const bf16x8*)&qbase[(int64_t)j * 16 * NPAD];

  __syncthreads();   // w_lds ready

#define SCORE_BODY(QF, H)                                                      \
  {                                                                            \
    float wv[4];                                                               \
    _Pragma("unroll") for (int j = 0; j < 4; ++j)                              \
        wv[j] = w_lds[H][wq * 64 + j * 16 + l15];                              \
    _Pragma("unroll") for (int i = 0; i < 4; ++i)                              \
    _Pragma("unroll") for (int j = 0; j < 4; ++j) {                            \
      f32x4 t = __builtin_amdgcn_mfma_f32_16x16x32_bf16(ka[i], QF[j], z0, 0, 0, 0); \
      _Pragma("unroll") for (int r = 0; r < 4; ++r)                            \
          acc[i][j][r] = fmaf(wv[j], fabsf(t[r]), acc[i][j][r]);               \
    }                                                                          \
  }

  for (int h = 0; h < 16; h += 2) {
#pragma unroll
    for (int j = 0; j < 4; ++j)          // prefetch h+1
      qb[j] = *(const bf16x8*)&qbase[(int64_t)j * 16 * NPAD + (h + 1) * 32];
    SCORE_BODY(qa, h)
    if (h + 2 < 16) {
#pragma unroll
      for (int j = 0; j < 4; ++j)        // prefetch h+2
        qa[j] = *(const bf16x8*)&qbase[(int64_t)j * 16 * NPAD + (h + 2) * 32];
    }
    SCORE_BODY(qb, h + 1)
  }
#undef SCORE_BODY

#pragma unroll
  for (int i = 0; i < 4; ++i)
#pragma unroll
    for (int j = 0; j < 4; ++j) {
      int q = qtile * 128 + wq * 64 + j * 16 + l15;
      int k = kt * 128 + wk * 64 + i * 16 + quad * 4;
      float4 v = make_float4(acc[i][j][0], acc[i][j][1], acc[i][j][2], acc[i][j][3]);
      *(float4*)&out[((int64_t)b * 4096 + q) * 4096 + k] = v;
    }
}

extern "C" void kernel_launch(void* const* d_in, const int* in_sizes, int n_in,
                              void* d_out, int out_size, void* d_ws, size_t ws_size,
                              hipStream_t stream) {
  const float* x  = (const float*)d_in[0];
  const float* Wq = (const float*)d_in[1];
  const float* Wk = (const float*)d_in[2];
  const float* Ww = (const float*)d_in[3];
  float* out = (float*)d_out;

  char* ws = (char*)d_ws;
  unsigned short* xb   = (unsigned short*)ws;                 // 8192x2048 bf16 = 33,554,432
  unsigned short* Wp   = (unsigned short*)(ws + 33554432);    //  576x2048 bf16 =  2,359,296
  unsigned short* qkwb = (unsigned short*)(ws + 35913728);    // 8192x576  bf16 =  9,437,184
  float*          wf   = (float*)(ws + 45350912);             // 8192x16   fp32 =    524,288
  unsigned short* qt   = (unsigned short*)(ws + 45875200);    // 8192x32   bf16 =    524,288

  pack_kernel<<<17536, 256, 0, stream>>>(x, Wq, Wk, Ww, xb, Wp);
  gemm_proj<<<dim3(9, 64), 256, 0, stream>>>(xb, Wp, qkwb, wf);
  combine_kernel<<<256, 256, 0, stream>>>(qkwb, wf, qt);
  scores_kernel<<<dim3(32, 32, 2), 256, 0, stream>>>(qkwb, wf, qt, out);
}

// Round 3
// 330.488 us; speedup vs baseline: 2.1573x; 2.1573x over previous
//
#include <hip/hip_runtime.h>
#include <hip/hip_bf16.h>
#include <stdint.h>

// LightningIndexer: importance[b,q,k] = sum_h w[b,q,h] * relu( q_h[b,q,:] . kv[b,k,:] )
// B=2, T=4096, C=2048, H=16, D=32.
// Identity: w*relu(s) = (w/2)*s + (w/2)*|s|. Linear part = ONE extra MFMA set with
// Qt = sum_h (w_h/2) q_h (epilogue); abs part = one v_fma-with-|.|-modifier per elem.
// Pipeline: pack -> proj GEMM -> combine(Qt) -> fused scores.

typedef __attribute__((ext_vector_type(8))) short bf16x8;
typedef __attribute__((ext_vector_type(4))) float f32x4;

#define NPAD 576   // 512 q | 32 k | 16 w | 16 zero pad  (9 tiles of 64)
#define KCOL 512
#define WCOL 544

__device__ __forceinline__ unsigned short f2bf(float f) {
  union { float f; unsigned u; } c; c.f = f;
  unsigned u = c.u;
  u += 0x7FFFu + ((u >> 16) & 1u);
  return (unsigned short)(u >> 16);
}
__device__ __forceinline__ float bf2f(unsigned short u) {
  union { unsigned u; float f; } c; c.u = ((unsigned)u) << 16;
  return c.f;
}
__device__ __forceinline__ void async_copy16(void* lds, const void* g) {
  __builtin_amdgcn_global_load_lds(
      (const __attribute__((address_space(1))) unsigned*)g,
      (__attribute__((address_space(3))) unsigned*)lds, 16, 0, 0);
}

// ---------------- kernel 1: cast x to bf16, pack Wq/Wk/Ww (+zero pad) ----------------
__global__ __launch_bounds__(256) void pack_kernel(
    const float* __restrict__ x, const float* __restrict__ Wq,
    const float* __restrict__ Wk, const float* __restrict__ Ww,
    unsigned short* __restrict__ xb, unsigned short* __restrict__ Wp) {
  const int64_t NX4 = 16777216 / 4;
  int64_t i = (int64_t)blockIdx.x * 256 + threadIdx.x;
  if (i < NX4) {
    float4 v = ((const float4*)x)[i];
    ushort4 o;
    o.x = f2bf(v.x); o.y = f2bf(v.y); o.z = f2bf(v.z); o.w = f2bf(v.w);
    ((ushort4*)xb)[i] = o;
  } else {
    int p = (int)(i - NX4);                  // 0 .. 576*512-1
    int row = p >> 9;
    int col = (p & 511) << 2;
    float4 v = make_float4(0.f, 0.f, 0.f, 0.f);
    if (row < 512)      v = *(const float4*)(Wq + (int64_t)row * 2048 + col);
    else if (row < 544) v = *(const float4*)(Wk + (int64_t)(row - 512) * 2048 + col);
    else if (row < 560) v = *(const float4*)(Ww + (int64_t)(row - 544) * 2048 + col);
    ushort4 o;
    o.x = f2bf(v.x); o.y = f2bf(v.y); o.z = f2bf(v.z); o.w = f2bf(v.w);
    ((ushort4*)Wp)[p] = o;
  }
}

// ---------------- kernel 2: qkw = x @ Wp^T  (8192 x 576 x 2048, bf16 MFMA) ----------------
// tile 128m x 64n, BK=64 (two k-half LDS tiles keep the lane-contiguous LDS layout).
__global__ __launch_bounds__(256) void gemm_proj(
    const unsigned short* __restrict__ xb, const unsigned short* __restrict__ Wp,
    unsigned short* __restrict__ qkwb, float* __restrict__ wf) {
  __shared__ short lA[2 * 128 * 32];   // 16 KB, [kh][row][32]
  __shared__ short lB[2 * 64 * 32];    //  8 KB
  const int tid = threadIdx.x;
  const int lane = tid & 63;
  const int l15 = lane & 15, quad = lane >> 4;
  const int wm = tid >> 6;             // wave id = m-strip (4 x 32 rows)
  const int n0 = blockIdx.x * 64, m0 = blockIdx.y * 128;

  const unsigned short* gA[4];
  const unsigned short* gB[2];
  int cA[4], cB[2];
#pragma unroll
  for (int u = 0; u < 4; ++u) {
    int c = tid + u * 256;
    cA[u] = c;
    int kh = c >> 9, row = (c >> 2) & 127, cc = c & 3;
    gA[u] = xb + (int64_t)(m0 + row) * 2048 + kh * 32 + cc * 8;
  }
#pragma unroll
  for (int u = 0; u < 2; ++u) {
    int c = tid + u * 256;
    cB[u] = c;
    int kh = c >> 8, row = (c >> 2) & 63, cc = c & 3;
    gB[u] = Wp + (int64_t)(n0 + row) * 2048 + kh * 32 + cc * 8;
  }

  f32x4 acc[2][4] = {};   // wave tile 32m x 64n

  for (int kt = 0; kt < 32; ++kt) {
    const int ko = kt * 64;
#pragma unroll
    for (int u = 0; u < 4; ++u) async_copy16(&lA[cA[u] * 8], gA[u] + ko);
#pragma unroll
    for (int u = 0; u < 2; ++u) async_copy16(&lB[cB[u] * 8], gB[u] + ko);
    __syncthreads();
#pragma unroll
    for (int ks = 0; ks < 2; ++ks) {
      bf16x8 af[2], bfr[4];
#pragma unroll
      for (int i = 0; i < 2; ++i)
        af[i] = *(const bf16x8*)&lA[(ks * 128 + wm * 32 + i * 16 + l15) * 32 + quad * 8];
#pragma unroll
      for (int j = 0; j < 4; ++j)
        bfr[j] = *(const bf16x8*)&lB[(ks * 64 + j * 16 + l15) * 32 + quad * 8];
#pragma unroll
      for (int i = 0; i < 2; ++i)
#pragma unroll
        for (int j = 0; j < 4; ++j)
          acc[i][j] = __builtin_amdgcn_mfma_f32_16x16x32_bf16(af[i], bfr[j], acc[i][j], 0, 0, 0);
    }
    __syncthreads();
  }

#pragma unroll
  for (int i = 0; i < 2; ++i)
#pragma unroll
    for (int j = 0; j < 4; ++j)
#pragma unroll
      for (int r = 0; r < 4; ++r) {
        int m = m0 + wm * 32 + i * 16 + quad * 4 + r;
        int n = n0 + j * 16 + l15;
        float v = acc[i][j][r];
        qkwb[(int64_t)m * NPAD + n] = f2bf(v);
        if (n >= WCOL && n < WCOL + 16) wf[m * 16 + (n - WCOL)] = 0.5f * v;  // w/2, fp32
      }
}

// ---------------- kernel 3: Qt[m,:] = sum_h (w_h/2) * q_h[m,:]  (8192 x 32 bf16) --------
__global__ __launch_bounds__(256) void combine_kernel(
    const unsigned short* __restrict__ qkwb, const float* __restrict__ wf,
    unsigned short* __restrict__ qt) {
  int gid = blockIdx.x * 256 + threadIdx.x;   // 65536 threads
  int m = gid >> 3, dq = (gid & 7) * 4;
  const unsigned short* qrow = qkwb + (int64_t)m * NPAD + dq;
  float s0 = 0, s1 = 0, s2 = 0, s3 = 0;
#pragma unroll
  for (int h = 0; h < 16; ++h) {
    ushort4 qv = *(const ushort4*)(qrow + h * 32);
    float u = wf[m * 16 + h];
    s0 += u * bf2f(qv.x); s1 += u * bf2f(qv.y);
    s2 += u * bf2f(qv.z); s3 += u * bf2f(qv.w);
  }
  ushort4 o; o.x = f2bf(s0); o.y = f2bf(s1); o.z = f2bf(s2); o.w = f2bf(s3);
  *(ushort4*)(qt + (int64_t)m * 32 + dq) = o;
}

// ---------------- kernel 4: fused scores ----------------
// out[q,k] = sum_h wv[q,h]*|q_h[q,:].k[k,:]|  (h loop)  +  Qt[q,:].k[k,:]  (epilogue MFMA)
__global__ __launch_bounds__(256) void scores_kernel(
    const unsigned short* __restrict__ qkwb, const float* __restrict__ wf,
    const unsigned short* __restrict__ qt, float* __restrict__ out) {
  const int kt = blockIdx.x, qtile = blockIdx.y, b = blockIdx.z;
  const int tid = threadIdx.x;
  const int lane = tid & 63;
  const int l15 = lane & 15, quad = lane >> 4;
  const int wave = tid >> 6;
  const int wk = wave & 1, wq = wave >> 1;

  __shared__ float w_lds[16][132];           // [h][q_local], wv = w/2

  const int qrow0 = b * 4096 + qtile * 128;
  const int krow0 = b * 4096 + kt * 128;

  {  // stage wv tile transposed: 128 q x 16 h fp32
    const float4* ws = (const float4*)(wf + (int64_t)qrow0 * 16);
#pragma unroll
    for (int r = 0; r < 2; ++r) {
      int f = tid * 2 + r;
      float4 v = ws[f];
      int row = f >> 2, hb = (f & 3) * 4;
      w_lds[hb + 0][row] = v.x; w_lds[hb + 1][row] = v.y;
      w_lds[hb + 2][row] = v.z; w_lds[hb + 3][row] = v.w;
    }
  }

  // K fragments (shared across heads + linear term), register-resident
  bf16x8 ka[4];
#pragma unroll
  for (int i = 0; i < 4; ++i) {
    int kk = krow0 + wk * 64 + i * 16 + l15;
    ka[i] = *(const bf16x8*)&qkwb[(int64_t)kk * NPAD + KCOL + quad * 8];
  }

  const f32x4 z0 = {0.f, 0.f, 0.f, 0.f};
  f32x4 acc[4][4] = {};   // zero-init -> AGPR placement

  const unsigned short* qbase =
      qkwb + (int64_t)(qrow0 + wq * 64 + l15) * NPAD + quad * 8;

  bf16x8 qa[4], qb[4];
#pragma unroll
  for (int j = 0; j < 4; ++j) qa[j] = *(const bf16x8*)&qbase[(int64_t)j * 16 * NPAD];

  __syncthreads();   // w_lds ready

#define SCORE_BODY(QF, H)                                                      \
  {                                                                            \
    float wv[4];                                                               \
    _Pragma("unroll") for (int j = 0; j < 4; ++j)                              \
        wv[j] = w_lds[H][wq * 64 + j * 16 + l15];                              \
    _Pragma("unroll") for (int i = 0; i < 4; ++i)                              \
    _Pragma("unroll") for (int j = 0; j < 4; ++j) {                            \
      f32x4 t = __builtin_amdgcn_mfma_f32_16x16x32_bf16(ka[i], QF[j], z0, 0, 0, 0); \
      _Pragma("unroll") for (int r = 0; r < 4; ++r)                            \
          acc[i][j][r] = fmaf(wv[j], fabsf(t[r]), acc[i][j][r]);               \
    }                                                                          \
  }

#pragma unroll 1
  for (int h = 0; h < 16; h += 2) {
#pragma unroll
    for (int j = 0; j < 4; ++j)          // prefetch h+1
      qb[j] = *(const bf16x8*)&qbase[(int64_t)j * 16 * NPAD + (h + 1) * 32];
    SCORE_BODY(qa, h)
#pragma unroll
    for (int j = 0; j < 4; ++j)          // prefetch h+2 (h=14 reads k/w cols: in-bounds, unused)
      qa[j] = *(const bf16x8*)&qbase[(int64_t)j * 16 * NPAD + (h + 2) * 32];
    SCORE_BODY(qb, h + 1)
  }
#undef SCORE_BODY

  // epilogue: linear term acc += Qt . k
#pragma unroll
  for (int j = 0; j < 4; ++j) {
    bf16x8 qtf = *(const bf16x8*)&qt[(int64_t)(qrow0 + wq * 64 + j * 16 + l15) * 32 + quad * 8];
#pragma unroll
    for (int i = 0; i < 4; ++i) {
      f32x4 t = __builtin_amdgcn_mfma_f32_16x16x32_bf16(ka[i], qtf, z0, 0, 0, 0);
#pragma unroll
      for (int r = 0; r < 4; ++r) acc[i][j][r] += t[r];
    }
  }

#pragma unroll
  for (int i = 0; i < 4; ++i)
#pragma unroll
    for (int j = 0; j < 4; ++j) {
      int q = qtile * 128 + wq * 64 + j * 16 + l15;
      int k = kt * 128 + wk * 64 + i * 16 + quad * 4;
      float4 v = make_float4(acc[i][j][0], acc[i][j][1], acc[i][j][2], acc[i][j][3]);
      *(float4*)&out[((int64_t)b * 4096 + q) * 4096 + k] = v;
    }
}

extern "C" void kernel_launch(void* const* d_in, const int* in_sizes, int n_in,
                              void* d_out, int out_size, void* d_ws, size_t ws_size,
                              hipStream_t stream) {
  const float* x  = (const float*)d_in[0];
  const float* Wq = (const float*)d_in[1];
  const float* Wk = (const float*)d_in[2];
  const float* Ww = (const float*)d_in[3];
  float* out = (float*)d_out;

  char* ws = (char*)d_ws;
  unsigned short* xb   = (unsigned short*)ws;                 // 8192x2048 bf16 = 33,554,432
  unsigned short* Wp   = (unsigned short*)(ws + 33554432);    //  576x2048 bf16 =  2,359,296
  unsigned short* qkwb = (unsigned short*)(ws + 35913728);    // 8192x576  bf16 =  9,437,184
  float*          wf   = (float*)(ws + 45350912);             // 8192x16   fp32 =    524,288
  unsigned short* qt   = (unsigned short*)(ws + 45875200);    // 8192x32   bf16 =    524,288

  pack_kernel<<<17536, 256, 0, stream>>>(x, Wq, Wk, Ww, xb, Wp);
  gemm_proj<<<dim3(9, 64), 256, 0, stream>>>(xb, Wp, qkwb, wf);
  combine_kernel<<<256, 256, 0, stream>>>(qkwb, wf, qt);
  scores_kernel<<<dim3(32, 32, 2), 256, 0, stream>>>(qkwb, wf, qt, out);
}